// Round 10
// baseline (151.079 us; speedup 1.0000x reference)
//
#include <hip/hip_runtime.h>
#include <stdint.h>

#define NT 5
#define NC 32
#define NH 4
#define HW 4096             // 64*64
#define NPIX 40960          // (b*t)*HW
#define QS 0.51006972789f   // (1/sqrt(8)) * log2(e): fold scale + ln->log2 into q
#define EBIAS 12.0f         // softmax shift: p = 2^(e-EBIAS); cancels in acc/l
#define NINF (-__builtin_inff())

typedef _Float16 half_t;
typedef half_t h2 __attribute__((ext_vector_type(2)));

static __device__ __forceinline__ h2 as_h2(uint32_t u) {
  union { uint32_t u; h2 h; } c; c.u = u; return c.h;
}
static __device__ __forceinline__ uint32_t pack_h2(float a, float b) {
  union { h2 h; uint32_t u; } c;
  c.h.x = (half_t)a; c.h.y = (half_t)b;
  return c.u;
}

#if __has_builtin(__builtin_amdgcn_exp2f)
#define EXP2(x) __builtin_amdgcn_exp2f(x)
#else
#define EXP2(x) exp2f(x)
#endif

// dot8 with runtime init accumulator (carries -EBIAS and the 0/-inf masks free)
static __device__ __forceinline__ float dot8i(const uint4& a, const uint4& b, float c) {
#if __has_builtin(__builtin_amdgcn_fdot2)
  c = __builtin_amdgcn_fdot2(as_h2(a.x), as_h2(b.x), c, false);
  c = __builtin_amdgcn_fdot2(as_h2(a.y), as_h2(b.y), c, false);
  c = __builtin_amdgcn_fdot2(as_h2(a.z), as_h2(b.z), c, false);
  c = __builtin_amdgcn_fdot2(as_h2(a.w), as_h2(b.w), c, false);
  return c;
#else
  const h2 a0 = as_h2(a.x), a1 = as_h2(a.y), a2 = as_h2(a.z), a3 = as_h2(a.w);
  const h2 b0 = as_h2(b.x), b1 = as_h2(b.y), b2 = as_h2(b.z), b3 = as_h2(b.w);
  c = fmaf((float)a0.x, (float)b0.x, c);
  c = fmaf((float)a0.y, (float)b0.y, c);
  c = fmaf((float)a1.x, (float)b1.x, c);
  c = fmaf((float)a1.y, (float)b1.y, c);
  c = fmaf((float)a2.x, (float)b2.x, c);
  c = fmaf((float)a2.y, (float)b2.y, c);
  c = fmaf((float)a3.x, (float)b3.x, c);
  c = fmaf((float)a3.y, (float)b3.y, c);
  return c;
#endif
}

// ---------------- Kernel A: QKV projection (head per blockIdx.y) ------------
// q,k,v -> fp16-packed uint4 [bt][h][pix]; q prescaled by QS.
// Also zeroes the 36-plane fp32 accumulator (re-zeroed every call).
__global__ __launch_bounds__(256) void qkv_kernel(
    const float* __restrict__ x,
    const float* __restrict__ Wq, const float* __restrict__ Wk,
    const float* __restrict__ Wv,
    uint4* __restrict__ qf, uint4* __restrict__ kf, uint4* __restrict__ vf,
    float* __restrict__ accbuf)
{
  const int p   = blockIdx.x * 256 + threadIdx.x;   // 0..40959
  const int h   = blockIdx.y;
  const int bt  = p >> 12;
  const int pix = p & 4095;

  // zero accumulator: 36*NPIX floats == 9 per (thread, blockIdx.y)
  const int gid = (blockIdx.y * 160 + blockIdx.x) * 256 + threadIdx.x; // 0..163839
  #pragma unroll
  for (int i = 0; i < 9; ++i) accbuf[(size_t)i * 163840 + gid] = 0.f;

  const float* xp = x + (size_t)bt * (NC * HW) + pix;
  float xc[NC];
  #pragma unroll
  for (int c = 0; c < NC; ++c) xc[c] = xp[(size_t)c * HW];

  float qv[8], kv8[8], vv8[8];
  #pragma unroll
  for (int j = 0; j < 8; ++j) {
    const int o = h * 8 + j;
    float aq = 0.f, ak = 0.f, av = 0.f;
    #pragma unroll
    for (int c = 0; c < NC; ++c) {
      const float xv = xc[c];
      aq = fmaf(xv, Wq[o * NC + c], aq);
      ak = fmaf(xv, Wk[o * NC + c], ak);
      av = fmaf(xv, Wv[o * NC + c], av);
    }
    qv[j] = aq * QS; kv8[j] = ak; vv8[j] = av;
  }
  const size_t base = ((size_t)bt * NH + h) * HW + pix;
  uint4 qq, kk, vv;
  qq.x = pack_h2(qv[0], qv[1]);  qq.y = pack_h2(qv[2], qv[3]);
  qq.z = pack_h2(qv[4], qv[5]);  qq.w = pack_h2(qv[6], qv[7]);
  kk.x = pack_h2(kv8[0], kv8[1]); kk.y = pack_h2(kv8[2], kv8[3]);
  kk.z = pack_h2(kv8[4], kv8[5]); kk.w = pack_h2(kv8[6], kv8[7]);
  vv.x = pack_h2(vv8[0], vv8[1]); vv.y = pack_h2(vv8[2], vv8[3]);
  vv.z = pack_h2(vv8[4], vv8[5]); vv.w = pack_h2(vv8[6], vv8[7]);
  qf[base] = qq;
  kf[base] = kk;
  vf[base] = vv;
}

// ---------------- Kernel B: neighborhood attention, LDS-staged --------------
// Block = 128 thr = 2 waves; lanes = 64 x-positions; each wave owns FOUR query
// rows (y, y+D, y+2D, y+3D) sharing every (K,V) LDS read. One frame per block.
// Per-query row-activity folded into the dot init as 0/-inf (exp2(-inf)=0).
// V-accumulators packed fp16 with 2^-EBIAS bias; l in fp32; fp32 atomics out.
template <int R, int D>
static __device__ __forceinline__ void attn_body(
    int b, int t, int h, int s, int yb,
    const uint4* __restrict__ qf, const uint4* __restrict__ kf,
    const uint4* __restrict__ vf, float* __restrict__ accbuf,
    uint4* __restrict__ k_lds, uint4* __restrict__ v_lds)
{
  constexpr int NROWS = 8 + 2 * R;        // staged key rows (compressed space)
  constexpr int CMAX  = (D == 1) ? 64 : 32;  // compressed row/col count
  const int tid  = threadIdx.x;
  const int w    = tid >> 6;              // wave 0..1
  const int lane = tid & 63;

  const int y0c    = (D == 1) ? (yb * 8) : ((yb >> 1) * 8);  // compressed base row
  const int parity = (D == 1) ? 0 : (yb & 1);

  // ---- stage NROWS full-width K,V rows into LDS (coalesced) ----
  const uint4* kg = kf + (size_t)((b * NT + s) * NH + h) * HW;
  const uint4* vg = vf + (size_t)((b * NT + s) * NH + h) * HW;
  for (int idx = tid; idx < NROWS * 64; idx += 128) {
    const int r  = idx >> 6, xs = idx & 63;
    int yc = y0c + r - R;
    yc = yc < 0 ? 0 : (yc > CMAX - 1 ? CMAX - 1 : yc);  // clamp; masked at compute
    const int ys  = (D == 1) ? yc : (parity + 2 * yc);
    const int pos = (D == 1) ? xs : ((xs & 1) * 32 + (xs >> 1));
    k_lds[r * 64 + pos] = kg[ys * 64 + xs];
    v_lds[r * 64 + pos] = vg[ys * 64 + xs];
  }
  __syncthreads();

  const int xpar = lane >> 5;                        // D2 x-parity
  const int cb   = (D == 1) ? lane : (lane & 31);    // compressed x
  const int x    = (D == 1) ? lane : (2 * (lane & 31) + xpar);

  // 4 query rows for this wave (compressed rows w*4 + i)
  int ypix[4];
  const uint4* qp = qf + (size_t)((b * NT + t) * NH + h) * HW;
  uint4 q[4];
  #pragma unroll
  for (int i = 0; i < 4; ++i) {
    const int yc = y0c + w * 4 + i;
    const int y  = (D == 1) ? yc : (parity + 2 * yc);
    ypix[i] = y * 64 + x;
    q[i] = qp[ypix[i]];
  }

  float l[4] = {0.f, 0.f, 0.f, 0.f};
  h2 a[4][4];
  const h2 z2 = { (half_t)0.f, (half_t)0.f };
  #pragma unroll
  for (int i = 0; i < 4; ++i)
    #pragma unroll
    for (int j = 0; j < 4; ++j) a[i][j] = z2;

  #pragma unroll 1
  for (int u = 0; u < 2 * R + 4; ++u) {              // key-row sweep, 4-query shared
    const int kyc = y0c + w * 4 + u - R;             // compressed key row
    if ((unsigned)kyc >= (unsigned)CMAX) continue;   // wave-uniform OOB skip
    // per-query activity: query i uses key rows [i, i+2R] in u-space
    float bi[4];
    #pragma unroll
    for (int i = 0; i < 4; ++i)
      bi[i] = (u >= i && u <= i + 2 * R) ? -EBIAS : NINF;
    const uint4* kr = k_lds + (w * 4 + u) * 64;
    const uint4* vr = v_lds + (w * 4 + u) * 64;
    #pragma unroll
    for (int dx = -R; dx <= R; ++dx) {
      const int  cx  = cb + dx;
      const bool okx = (unsigned)cx < (unsigned)CMAX;
      const int  cc  = okx ? cx : 0;
      const int  pos = (D == 1) ? cc : (xpar * 32 + cc);
      const uint4 kk = kr[pos];
      const uint4 vv = vr[pos];
      const h2 w0 = as_h2(vv.x), w1 = as_h2(vv.y), w2 = as_h2(vv.z), w3 = as_h2(vv.w);
      const float eo = okx ? 0.f : NINF;             // x-mask, shared by 4 queries
      #pragma unroll
      for (int i = 0; i < 4; ++i) {
        const float e = dot8i(q[i], kk, bi[i] + eo); // -inf -> p = 0
        const float p = EXP2(e);
        l[i] += p;
        const half_t ph = (half_t)p;
        const h2 p2 = { ph, ph };
        a[i][0] += p2 * w0; a[i][1] += p2 * w1;
        a[i][2] += p2 * w2; a[i][3] += p2 * w3;
      }
    }
  }

  // ---- accumulate frame-partials: accbuf[h][comp(9)][btpix] ----
  const int btbase = (b * NT + t) * HW;
  float* ab = accbuf + (size_t)(h * 9) * NPIX;
  #pragma unroll
  for (int i = 0; i < 4; ++i) {
    const int bp = btbase + ypix[i];
    #pragma unroll
    for (int j = 0; j < 4; ++j) {
      atomicAdd(&ab[(size_t)(2 * j)     * NPIX + bp], (float)a[i][j].x);
      atomicAdd(&ab[(size_t)(2 * j + 1) * NPIX + bp], (float)a[i][j].y);
    }
    atomicAdd(&ab[(size_t)8 * NPIX + bp], l[i]);
  }
}

__global__ __launch_bounds__(128) void attn_kernel(
    const uint4* __restrict__ qf, const uint4* __restrict__ kf,
    const uint4* __restrict__ vf, float* __restrict__ accbuf)
{
  __shared__ uint4 k_lds[16 * 64];   // 16 KB
  __shared__ uint4 v_lds[16 * 64];   // 16 KB
  const int bid = blockIdx.x;        // 1600 = 10(bt) * 5(s) * 8(yb) * 4(h)
  const int h   = bid & 3;           // head in low bits -> R3/R4 mix per CU
  int r = bid >> 2;
  const int yb = r & 7; r >>= 3;
  const int s  = r % 5;
  const int bt = r / 5;
  const int t = bt % NT, b = bt / NT;
  if      (h == 0) attn_body<3, 1>(b, t, 0, s, yb, qf, kf, vf, accbuf, k_lds, v_lds);
  else if (h == 1) attn_body<3, 2>(b, t, 1, s, yb, qf, kf, vf, accbuf, k_lds, v_lds);
  else if (h == 2) attn_body<4, 1>(b, t, 2, s, yb, qf, kf, vf, accbuf, k_lds, v_lds);
  else             attn_body<4, 2>(b, t, 3, s, yb, qf, kf, vf, accbuf, k_lds, v_lds);
}

// ---------------- Kernel C: normalize + output projection + residual --------
__global__ __launch_bounds__(64) void proj_kernel(
    const float* __restrict__ accbuf, const float* __restrict__ x,
    const float* __restrict__ Wo, float* __restrict__ out)
{
  const int p   = blockIdx.x * 64 + threadIdx.x;   // btpix 0..40959
  const int bt  = p >> 12;
  const int pix = p & 4095;

  float oc[32];
  #pragma unroll
  for (int h = 0; h < NH; ++h) {
    const float* ab = accbuf + (size_t)(h * 9) * NPIX + p;
    float a[8];
    #pragma unroll
    for (int i = 0; i < 8; ++i) a[i] = ab[(size_t)i * NPIX];
    const float inv = 1.0f / ab[(size_t)8 * NPIX];
    #pragma unroll
    for (int i = 0; i < 8; ++i) oc[h * 8 + i] = a[i] * inv;
  }

  const float* xp = x + (size_t)bt * (NC * HW) + pix;
  float* yp = out + (size_t)bt * (NC * HW) + pix;
  #pragma unroll
  for (int o = 0; o < NC; ++o) {
    float acc = xp[(size_t)o * HW];                 // residual
    #pragma unroll
    for (int c = 0; c < NC; ++c)
      acc = fmaf(oc[c], Wo[o * NC + c], acc);
    yp[(size_t)o * HW] = acc;
  }
}

extern "C" void kernel_launch(void* const* d_in, const int* in_sizes, int n_in,
                              void* d_out, int out_size, void* d_ws, size_t ws_size,
                              hipStream_t stream)
{
  const float* x  = (const float*)d_in[0];
  const float* Wq = (const float*)d_in[1];
  const float* Wk = (const float*)d_in[2];
  const float* Wv = (const float*)d_in[3];
  const float* Wo = (const float*)d_in[4];

  char* ws = (char*)d_ws;
  uint4* qf  = (uint4*)ws;                          // 2,621,440 B
  uint4* kf  = (uint4*)(ws + 2621440);              // 2,621,440 B
  uint4* vf  = (uint4*)(ws + 2 * 2621440);          // 2,621,440 B
  float* acc = (float*)(ws + 3 * 2621440);          // 5,898,240 B (36 planes)

  qkv_kernel<<<dim3(160, 4), 256, 0, stream>>>(x, Wq, Wk, Wv, qf, kf, vf, acc);
  attn_kernel<<<1600, 128, 0, stream>>>(qf, kf, vf, acc);
  proj_kernel<<<640, 64, 0, stream>>>(acc, x, Wo, (float*)d_out);
}

// Round 11
// 133.313 us; speedup vs baseline: 1.1333x; 1.1333x over previous
//
#include <hip/hip_runtime.h>
#include <stdint.h>

#define NT 5
#define NC 32
#define NH 4
#define HW 4096             // 64*64
#define NPIX 40960          // (b*t)*HW
#define QS 0.51006972789f   // (1/sqrt(8)) * log2(e): fold scale + ln->log2 into q
#define EBIAS 12.0f         // softmax shift: p = 2^(e-EBIAS); cancels in acc/l

typedef _Float16 half_t;
typedef half_t h2 __attribute__((ext_vector_type(2)));

static __device__ __forceinline__ h2 as_h2(uint32_t u) {
  union { uint32_t u; h2 h; } c; c.u = u; return c.h;
}
static __device__ __forceinline__ uint32_t pack_h2(float a, float b) {
  union { h2 h; uint32_t u; } c;
  c.h.x = (half_t)a; c.h.y = (half_t)b;
  return c.u;
}

#if __has_builtin(__builtin_amdgcn_exp2f)
#define EXP2(x) __builtin_amdgcn_exp2f(x)
#else
#define EXP2(x) exp2f(x)
#endif

// dot8 with accumulator initialized at -EBIAS: e = q.k - 12, rides for free.
static __device__ __forceinline__ float dot8b(const uint4& a, const uint4& b) {
#if __has_builtin(__builtin_amdgcn_fdot2)
  float c = -EBIAS;
  c = __builtin_amdgcn_fdot2(as_h2(a.x), as_h2(b.x), c, false);
  c = __builtin_amdgcn_fdot2(as_h2(a.y), as_h2(b.y), c, false);
  c = __builtin_amdgcn_fdot2(as_h2(a.z), as_h2(b.z), c, false);
  c = __builtin_amdgcn_fdot2(as_h2(a.w), as_h2(b.w), c, false);
  return c;
#else
  const h2 a0 = as_h2(a.x), a1 = as_h2(a.y), a2 = as_h2(a.z), a3 = as_h2(a.w);
  const h2 b0 = as_h2(b.x), b1 = as_h2(b.y), b2 = as_h2(b.z), b3 = as_h2(b.w);
  float c = -EBIAS;
  c = fmaf((float)a0.x, (float)b0.x, c);
  c = fmaf((float)a0.y, (float)b0.y, c);
  c = fmaf((float)a1.x, (float)b1.x, c);
  c = fmaf((float)a1.y, (float)b1.y, c);
  c = fmaf((float)a2.x, (float)b2.x, c);
  c = fmaf((float)a2.y, (float)b2.y, c);
  c = fmaf((float)a3.x, (float)b3.x, c);
  c = fmaf((float)a3.y, (float)b3.y, c);
  return c;
#endif
}

// ---------------- Kernel A: QKV projection (head per blockIdx.y) ------------
// q,k,v -> fp16-packed uint4 [bt][h][pix]; q prescaled by QS.
__global__ __launch_bounds__(256) void qkv_kernel(
    const float* __restrict__ x,
    const float* __restrict__ Wq, const float* __restrict__ Wk,
    const float* __restrict__ Wv,
    uint4* __restrict__ qf, uint4* __restrict__ kf, uint4* __restrict__ vf)
{
  const int p   = blockIdx.x * 256 + threadIdx.x;   // 0..40959
  const int h   = blockIdx.y;
  const int bt  = p >> 12;
  const int pix = p & 4095;

  const float* xp = x + (size_t)bt * (NC * HW) + pix;
  float xc[NC];
  #pragma unroll
  for (int c = 0; c < NC; ++c) xc[c] = xp[(size_t)c * HW];

  float qv[8], kv8[8], vv8[8];
  #pragma unroll
  for (int j = 0; j < 8; ++j) {
    const int o = h * 8 + j;
    float aq = 0.f, ak = 0.f, av = 0.f;
    #pragma unroll
    for (int c = 0; c < NC; ++c) {
      const float xv = xc[c];
      aq = fmaf(xv, Wq[o * NC + c], aq);
      ak = fmaf(xv, Wk[o * NC + c], ak);
      av = fmaf(xv, Wv[o * NC + c], av);
    }
    qv[j] = aq * QS; kv8[j] = ak; vv8[j] = av;
  }
  const size_t base = ((size_t)bt * NH + h) * HW + pix;
  uint4 qq, kk, vv;
  qq.x = pack_h2(qv[0], qv[1]);  qq.y = pack_h2(qv[2], qv[3]);
  qq.z = pack_h2(qv[4], qv[5]);  qq.w = pack_h2(qv[6], qv[7]);
  kk.x = pack_h2(kv8[0], kv8[1]); kk.y = pack_h2(kv8[2], kv8[3]);
  kk.z = pack_h2(kv8[4], kv8[5]); kk.w = pack_h2(kv8[6], kv8[7]);
  vv.x = pack_h2(vv8[0], vv8[1]); vv.y = pack_h2(vv8[2], vv8[3]);
  vv.z = pack_h2(vv8[4], vv8[5]); vv.w = pack_h2(vv8[6], vv8[7]);
  qf[base] = qq;
  kf[base] = kk;
  vf[base] = vv;
}

// ---------------- Kernel B: neighborhood attention, LDS-staged --------------
// EXACT round-9 inner loop (pair of query rows per wave, 256 thr, 4 waves).
// Epilogue changed: frame-partials written as fp16x8 uint4 + fp32 l, plain
// stores (each slot written exactly once) instead of 18 global atomics.
template <int R, int D>
static __device__ __forceinline__ void attn_body(
    int b, int t, int h, int s, int yb,
    const uint4* __restrict__ qf, const uint4* __restrict__ kf,
    const uint4* __restrict__ vf,
    uint4* __restrict__ pa, float* __restrict__ pl,
    uint4* __restrict__ k_lds, uint4* __restrict__ v_lds)
{
  constexpr int LS    = 2 * R + 1;
  constexpr int NROWS = 8 + 2 * R;        // staged key rows (step D)
  const int tid  = threadIdx.x;
  const int w    = tid >> 6;              // wave 0..3
  const int lane = tid & 63;

  // first query row of this block (D2: yb&1 = row parity, 8 same-parity rows)
  const int y0 = (D == 1) ? (yb * 8) : ((yb & 1) + 2 * ((yb >> 1) * 8));

  // ---- stage NROWS full-width K,V rows into LDS (coalesced) ----
  const uint4* kg = kf + (size_t)((b * NT + s) * NH + h) * HW;
  const uint4* vg = vf + (size_t)((b * NT + s) * NH + h) * HW;
  for (int idx = tid; idx < NROWS * 64; idx += 256) {
    const int r  = idx >> 6, xs = idx & 63;
    int ys = y0 + (r - R) * D;
    ys = ys < 0 ? 0 : (ys > 63 ? 63 : ys);          // clamp; masked at compute
    const int pos = (D == 1) ? xs : ((xs & 1) * 32 + (xs >> 1));
    k_lds[r * 64 + pos] = kg[ys * 64 + xs];
    v_lds[r * 64 + pos] = vg[ys * 64 + xs];
  }
  __syncthreads();

  const int xp = lane >> 5;                          // D2 x-parity
  const int cb = (D == 1) ? lane : (lane & 31);      // compressed x
  const int x  = (D == 1) ? lane : (2 * (lane & 31) + xp);
  const int yA = y0 + 2 * w * D;
  const int yB = yA + D;
  const int pixA = yA * 64 + x, pixB = yB * 64 + x;

  const uint4* qp = qf + (size_t)((b * NT + t) * NH + h) * HW;
  const uint4 qA = qp[pixA];
  const uint4 qB = qp[pixB];

  float lA = 0.f, lB = 0.f;
  h2 aA[4], aB[4];
  const h2 z2 = { (half_t)0.f, (half_t)0.f };
  #pragma unroll
  for (int i = 0; i < 4; ++i) { aA[i] = z2; aB[i] = z2; }

  #pragma unroll 1
  for (int u = 0; u <= LS; ++u) {                    // key-row sweep, pair-shared
    const bool okA = (u < LS) && ((unsigned)(yA + (u - R) * D) < 64u);
    const bool okB = (u > 0)  && ((unsigned)(yB + (u - 1 - R) * D) < 64u);
    if (!(okA || okB)) continue;                     // wave-uniform skip
    const float mA = okA ? 1.f : 0.f, mB = okB ? 1.f : 0.f;
    const uint4* kr = k_lds + (2 * w + u) * 64;
    const uint4* vr = v_lds + (2 * w + u) * 64;
    #pragma unroll
    for (int dx = -R; dx <= R; ++dx) {
      const int  cx  = cb + dx;
      const bool okx = (unsigned)cx < (D == 1 ? 64u : 32u);
      const int  cc  = okx ? cx : 0;
      const int  pos = (D == 1) ? cc : (xp * 32 + cc);
      const uint4 kk = kr[pos];
      const uint4 vv = vr[pos];
      const h2 w0 = as_h2(vv.x), w1 = as_h2(vv.y), w2 = as_h2(vv.z), w3 = as_h2(vv.w);
      const float eA = dot8b(qA, kk);                // e - EBIAS, bias free
      const float eB = dot8b(qB, kk);
      const float pA = (okx ? mA : 0.f) * EXP2(eA);
      const float pB = (okx ? mB : 0.f) * EXP2(eB);
      lA += pA; lB += pB;
      const half_t pAh = (half_t)pA, pBh = (half_t)pB;
      const h2 pA2 = { pAh, pAh }, pB2 = { pBh, pBh };
      aA[0] += pA2 * w0; aA[1] += pA2 * w1; aA[2] += pA2 * w2; aA[3] += pA2 * w3;
      aB[0] += pB2 * w0; aB[1] += pB2 * w1; aB[2] += pB2 * w2; aB[3] += pB2 * w3;
    }
  }

  // ---- store frame-partials: pa/pl [s][h][btpix], each written once ----
  const size_t plane = (size_t)(s * NH + h) * NPIX + (size_t)(b * NT + t) * HW;
  union { h2 hh[4]; uint4 u; } cA, cB;
  #pragma unroll
  for (int i = 0; i < 4; ++i) { cA.hh[i] = aA[i]; cB.hh[i] = aB[i]; }
  pa[plane + pixA] = cA.u;
  pa[plane + pixB] = cB.u;
  pl[plane + pixA] = lA;
  pl[plane + pixB] = lB;
}

__global__ __launch_bounds__(256) void attn_kernel(
    const uint4* __restrict__ qf, const uint4* __restrict__ kf,
    const uint4* __restrict__ vf, uint4* __restrict__ pa, float* __restrict__ pl)
{
  __shared__ uint4 k_lds[16 * 64];   // 16 KB
  __shared__ uint4 v_lds[16 * 64];   // 16 KB
  const int bid = blockIdx.x;        // 1600 = 10(bt) * 5(s) * 8(yb) * 4(h)
  const int h   = bid & 3;           // head in low bits -> R3/R4 mix per CU
  int r = bid >> 2;
  const int yb = r & 7; r >>= 3;
  const int s  = r % 5;
  const int bt = r / 5;
  const int t = bt % NT, b = bt / NT;
  if      (h == 0) attn_body<3, 1>(b, t, 0, s, yb, qf, kf, vf, pa, pl, k_lds, v_lds);
  else if (h == 1) attn_body<3, 2>(b, t, 1, s, yb, qf, kf, vf, pa, pl, k_lds, v_lds);
  else if (h == 2) attn_body<4, 1>(b, t, 2, s, yb, qf, kf, vf, pa, pl, k_lds, v_lds);
  else             attn_body<4, 2>(b, t, 3, s, yb, qf, kf, vf, pa, pl, k_lds, v_lds);
}

// ---------------- Kernel C: reduce partials + normalize + Wo + residual -----
__global__ __launch_bounds__(64) void proj_kernel(
    const uint4* __restrict__ pa, const float* __restrict__ pl,
    const float* __restrict__ x, const float* __restrict__ Wo,
    float* __restrict__ out)
{
  const int p   = blockIdx.x * 64 + threadIdx.x;   // btpix 0..40959
  const int bt  = p >> 12;
  const int pix = p & 4095;

  float oc[32];
  #pragma unroll
  for (int h = 0; h < NH; ++h) {
    float a[8], l = 0.f;
    #pragma unroll
    for (int i = 0; i < 8; ++i) a[i] = 0.f;
    #pragma unroll
    for (int s = 0; s < NT; ++s) {
      const size_t plane = (size_t)(s * NH + h) * NPIX + p;
      const uint4 v = pa[plane];
      l += pl[plane];
      const h2 v0 = as_h2(v.x), v1 = as_h2(v.y), v2 = as_h2(v.z), v3 = as_h2(v.w);
      a[0] += (float)v0.x; a[1] += (float)v0.y;
      a[2] += (float)v1.x; a[3] += (float)v1.y;
      a[4] += (float)v2.x; a[5] += (float)v2.y;
      a[6] += (float)v3.x; a[7] += (float)v3.y;
    }
    const float inv = 1.0f / l;
    #pragma unroll
    for (int i = 0; i < 8; ++i) oc[h * 8 + i] = a[i] * inv;
  }

  const float* xp = x + (size_t)bt * (NC * HW) + pix;
  float* yp = out + (size_t)bt * (NC * HW) + pix;
  #pragma unroll
  for (int o = 0; o < NC; ++o) {
    float acc = xp[(size_t)o * HW];                 // residual
    #pragma unroll
    for (int c = 0; c < NC; ++c)
      acc = fmaf(oc[c], Wo[o * NC + c], acc);
    yp[(size_t)o * HW] = acc;
  }
}

extern "C" void kernel_launch(void* const* d_in, const int* in_sizes, int n_in,
                              void* d_out, int out_size, void* d_ws, size_t ws_size,
                              hipStream_t stream)
{
  const float* x  = (const float*)d_in[0];
  const float* Wq = (const float*)d_in[1];
  const float* Wk = (const float*)d_in[2];
  const float* Wv = (const float*)d_in[3];
  const float* Wo = (const float*)d_in[4];

  char* ws = (char*)d_ws;
  uint4* qf = (uint4*)ws;                           //  2,621,440 B
  uint4* kf = (uint4*)(ws + 2621440);               //  2,621,440 B
  uint4* vf = (uint4*)(ws + 2 * 2621440);           //  2,621,440 B
  uint4* pa = (uint4*)(ws + 3 * 2621440);           // 13,107,200 B (fp16x8 partials)
  float* pl = (float*)(ws + 3 * 2621440 + 13107200); // 3,276,800 B (fp32 l)

  qkv_kernel<<<dim3(160, 4), 256, 0, stream>>>(x, Wq, Wk, Wv, qf, kf, vf);
  attn_kernel<<<1600, 256, 0, stream>>>(qf, kf, vf, pa, pl);
  proj_kernel<<<640, 64, 0, stream>>>(pa, pl, x, Wo, (float*)d_out);
}